// Round 5
// baseline (855.196 us; speedup 1.0000x reference)
//
#include <hip/hip_runtime.h>
#include <math.h>

#define Bc 4
#define Nc 256
#define Tc 128
#define Dc 512
#define Hc 8
#define HDc 64

// ---- measurement-round repeat factors (idempotent re-execution) ----
#define REP_MEAN 4
#define REP_ATTN 3

typedef float f4v __attribute__((ext_vector_type(4)));

// swizzled float4-unit index for 64x64 float tile stored as 1024 float4s
#define SWZ(row, k4) (((row) << 4) | ((k4) ^ (((row) >> 2) & 15)))

// ---------------- Kernel 1: x_repr = mean over T (+ Wo transpose) --------
__global__ __launch_bounds__(256) void mean_kernel(const float* __restrict__ x,
                                                   float* __restrict__ xr,
                                                   const float* __restrict__ Wo,
                                                   float* __restrict__ WoT) {
    __shared__ f4v red[256];
    const int bn = blockIdx.x;
    const int col = threadIdx.x & 127;
    const int half = threadIdx.x >> 7;
    for (int rep = 0; rep < REP_MEAN; ++rep) {
        const f4v* xp = (const f4v*)x + (size_t)bn * (Tc * Dc / 4)
                        + (size_t)(half * 64) * (Dc / 4) + col;
        f4v a[8];
#pragma unroll
        for (int u = 0; u < 8; ++u) a[u] = (f4v)(0.f);
        for (int t = 0; t < 64; t += 8) {
#pragma unroll
            for (int u = 0; u < 8; ++u)
                a[u] += __builtin_nontemporal_load(xp + (size_t)(t + u) * (Dc / 4));
        }
        f4v s = ((a[0] + a[1]) + (a[2] + a[3])) + ((a[4] + a[5]) + (a[6] + a[7]));
        red[threadIdx.x] = s;
        __syncthreads();
        if (threadIdx.x < 128) {
            f4v r = (red[threadIdx.x] + red[threadIdx.x + 128]) * (1.0f / Tc);
            ((f4v*)xr)[(size_t)bn * (Dc / 4) + threadIdx.x] = r;
        }
        if (bn < 16) {  // Wo transpose: rows bn*32..+31 -> WoT[k][j]
            const int r0 = bn * 32;
#pragma unroll 4
            for (int u = 0; u < 16; ++u) {
                const int job = u * 256 + threadIdx.x;
                const int r = job >> 7;        // 0..31
                const int k4 = job & 127;      // 0..127
                const float4 v = *(const float4*)&Wo[(size_t)(r0 + r) * Dc + k4 * 4];
                WoT[(size_t)(k4 * 4 + 0) * Dc + r0 + r] = v.x;
                WoT[(size_t)(k4 * 4 + 1) * Dc + r0 + r] = v.y;
                WoT[(size_t)(k4 * 4 + 2) * Dc + r0 + r] = v.z;
                WoT[(size_t)(k4 * 4 + 3) * Dc + r0 + r] = v.w;
            }
        }
        asm volatile("" ::: "memory");
        __syncthreads();
    }
}

// ---------------- GEMM core with register-prefetch pipeline --------------
__device__ __forceinline__ void gemm_core(const float* __restrict__ A,
                                          const float* __restrict__ W,
                                          int i0, int j0, float acc[4][4]) {
    __shared__ float4 As4[1024];
    __shared__ float4 Ws4[1024];
    const int tid = threadIdx.x;
    const int ty = tid >> 4, tx = tid & 15;
    float4 pa[4], pw[4];
#pragma unroll
    for (int p = 0; p < 4; ++p) {
        pa[p] = *(const float4*)&A[(size_t)(i0 + p * 16 + ty) * Dc + tx * 4];
        pw[p] = *(const float4*)&W[(size_t)(j0 + p * 16 + ty) * Dc + tx * 4];
    }
    for (int kb = 0; kb < 8; ++kb) {
#pragma unroll
        for (int p = 0; p < 4; ++p) {
            As4[SWZ(p * 16 + ty, tx)] = pa[p];
            Ws4[SWZ(p * 16 + ty, tx)] = pw[p];
        }
        __syncthreads();
        if (kb < 7) {
            const int k0 = (kb + 1) * 64;
#pragma unroll
            for (int p = 0; p < 4; ++p) {
                pa[p] = *(const float4*)&A[(size_t)(i0 + p * 16 + ty) * Dc + k0 + tx * 4];
                pw[p] = *(const float4*)&W[(size_t)(j0 + p * 16 + ty) * Dc + k0 + tx * 4];
            }
        }
#pragma unroll
        for (int kk4 = 0; kk4 < 16; ++kk4) {
            float4 a[4], w[4];
#pragma unroll
            for (int q = 0; q < 4; ++q) a[q] = As4[SWZ(ty * 4 + q, kk4)];
#pragma unroll
            for (int c = 0; c < 4; ++c) w[c] = Ws4[SWZ(tx * 4 + c, kk4)];
#pragma unroll
            for (int q = 0; q < 4; ++q)
#pragma unroll
                for (int c = 0; c < 4; ++c) {
                    acc[q][c] += a[q].x * w[c].x;
                    acc[q][c] += a[q].y * w[c].y;
                    acc[q][c] += a[q].z * w[c].z;
                    acc[q][c] += a[q].w * w[c].w;
                }
        }
        __syncthreads();
    }
}

// Fused QKV: grid (16, 24). K stored TRANSPOSED: Kt[((b*8+h)*64+hd)*256+n]
__global__ __launch_bounds__(256) void qkv_kernel(
    const float* __restrict__ xr, const float* __restrict__ Wq, const float* __restrict__ bq,
    const float* __restrict__ Wk, const float* __restrict__ bk,
    const float* __restrict__ Wv, const float* __restrict__ bv,
    float* __restrict__ Yq, float* __restrict__ Kt, float* __restrict__ Yv) {
    const int it = blockIdx.x;
    const int mat = blockIdx.y >> 3;
    const int jt = blockIdx.y & 7;
    const float* W = (mat == 0) ? Wq : (mat == 1) ? Wk : Wv;
    const float* bias = (mat == 0) ? bq : (mat == 1) ? bk : bv;
    const int i0 = it * 64, j0 = jt * 64;
    float acc[4][4] = {{0.f}};
    gemm_core(xr, W, i0, j0, acc);
    const int ty = threadIdx.x >> 4, tx = threadIdx.x & 15;
    if (mat == 1) {
        const int b = i0 >> 8;
        const int n0 = (i0 & 255) + ty * 4;
#pragma unroll
        for (int c = 0; c < 4; ++c) {
            const int j = j0 + tx * 4 + c;
            const float bj = bias[j];
            float4 v = make_float4(acc[0][c] + bj, acc[1][c] + bj,
                                   acc[2][c] + bj, acc[3][c] + bj);
            *(float4*)&Kt[(((size_t)b * Hc + jt) * HDc + (tx * 4 + c)) * Nc + n0] = v;
        }
    } else {
        float* Y = (mat == 0) ? Yq : Yv;
#pragma unroll
        for (int r = 0; r < 4; ++r) {
            const int i = i0 + ty * 4 + r;
            const int j = j0 + tx * 4;
            float4 o = make_float4(acc[r][0] + bias[j + 0], acc[r][1] + bias[j + 1],
                                   acc[r][2] + bias[j + 2], acc[r][3] + bias[j + 3]);
            *(float4*)&Y[(size_t)i * Dc + j] = o;
        }
    }
}

// ---------------- Kernel 3: attention + O-proj + T-broadcast -------------
__global__ __launch_bounds__(512) void attn_oproj_kernel(
    const float* __restrict__ Yq, const float* __restrict__ Kt,
    const float* __restrict__ Yv, const float* __restrict__ coords,
    const int* __restrict__ mask, const float* __restrict__ Wd1,
    const float* __restrict__ bd1, const float* __restrict__ Wd2,
    const float* __restrict__ bd2, const float* __restrict__ WoT,
    const float* __restrict__ bo, float* __restrict__ out) {
    const int b = blockIdx.x >> 6;
    const int n4 = (blockIdx.x & 63) * 4;    // 4 query rows per block
    const int tid = threadIdx.x;
    const int wid = tid >> 6, lane = tid & 63;
    const int h = wid;                       // wave = head

    __shared__ __align__(16) float sqf[4][512];     // q rows (all heads), scaled
    __shared__ __align__(16) float sw[8][4][256];   // softmax numerators
    __shared__ __align__(16) float sO[4][512];      // attention-out rows
    __shared__ __align__(16) float sOut[4][512];    // final out rows
    __shared__ float slat[256], slon[256], scl[256];
    __shared__ __align__(16) float swd1[64];
    __shared__ __align__(16) float sbd1[64];
    __shared__ __align__(16) float swd2[512];       // all 8 heads
    __shared__ int smk[256];

    for (int rep = 0; rep < REP_ATTN; ++rep) {
        {
            const float DEG = 0.017453292519943295f;
            if (tid < 256) {
                float la = coords[((size_t)b * Nc + tid) * 2 + 0] * DEG;
                float lo = coords[((size_t)b * Nc + tid) * 2 + 1] * DEG;
                slat[tid] = la; slon[tid] = lo; scl[tid] = __cosf(la);
                smk[tid] = mask[(size_t)b * Nc + tid];
            }
            if (tid < 64) {
                swd1[tid] = Wd1[tid];
                sbd1[tid] = bd1[tid];
            }
            swd2[tid] = Wd2[tid];
            const int row = tid >> 7, c4 = tid & 127;
            const float4 qv = *(const float4*)&Yq[((size_t)(b * Nc + n4 + row)) * Dc + c4 * 4];
            sqf[row][c4 * 4 + 0] = qv.x * 0.125f;
            sqf[row][c4 * 4 + 1] = qv.y * 0.125f;
            sqf[row][c4 * 4 + 2] = qv.z * 0.125f;
            sqf[row][c4 * 4 + 3] = qv.w * 0.125f;
        }
        __syncthreads();

        // ---- scores: lane owns m-strip lane*4..+3 for 4 queries ----
        const float4* ktp = (const float4*)(Kt + ((size_t)(b * Hc + h)) * HDc * Nc);
        f4v acc[4];
#pragma unroll
        for (int j = 0; j < 4; ++j) acc[j] = (f4v)(0.f);
#pragma unroll 8
        for (int k = 0; k < 64; ++k) {
            const float4 kv = ktp[k * 64 + lane];
            const f4v kvv = {kv.x, kv.y, kv.z, kv.w};
#pragma unroll
            for (int j = 0; j < 4; ++j) acc[j] += sqf[j][h * HDc + k] * kvv;
        }

        // ---- haversine distances for all 16 (j, jm) pairs ----
        const int mbase = lane * 4;
        float mlat[4], mlon[4], mcl[4];
        int mk[4];
#pragma unroll
        for (int jm = 0; jm < 4; ++jm) {
            mlat[jm] = slat[mbase + jm]; mlon[jm] = slon[mbase + jm];
            mcl[jm] = scl[mbase + jm];   mk[jm] = smk[mbase + jm];
        }
        float dist[4][4];
#pragma unroll
        for (int j = 0; j < 4; ++j) {
            const int n = n4 + j;
            const float lat1 = slat[n], lon1 = slon[n], cl1 = scl[n];
#pragma unroll
            for (int jm = 0; jm < 4; ++jm) {
                float sdlat = __sinf((mlat[jm] - lat1) * 0.5f);
                float sdlon = __sinf((mlon[jm] - lon1) * 0.5f);
                float a = sdlat * sdlat + cl1 * mcl[jm] * sdlon * sdlon;
                a = fminf(fmaxf(a, 0.f), 1.f);
                dist[j][jm] = 12742.0f * atan2f(sqrtf(a), sqrtf(1.0f - a));
            }
        }

        // ---- MLP bias: k4-outer, pairs-inner (strict k-ascending adds) ----
        float bias[4][4];
#pragma unroll
        for (int j = 0; j < 4; ++j)
#pragma unroll
            for (int jm = 0; jm < 4; ++jm) bias[j][jm] = 0.f;
#pragma unroll 4
        for (int k4 = 0; k4 < 16; ++k4) {
            const float4 w1 = *(const float4*)&swd1[k4 * 4];
            const float4 b1 = *(const float4*)&sbd1[k4 * 4];
            const float4 w2 = *(const float4*)&swd2[h * HDc + k4 * 4];
#pragma unroll
            for (int j = 0; j < 4; ++j)
#pragma unroll
                for (int jm = 0; jm < 4; ++jm) {
                    const float d = dist[j][jm];
                    float bacc = bias[j][jm];
                    bacc += fmaxf(d * w1.x + b1.x, 0.f) * w2.x;
                    bacc += fmaxf(d * w1.y + b1.y, 0.f) * w2.y;
                    bacc += fmaxf(d * w1.z + b1.z, 0.f) * w2.z;
                    bacc += fmaxf(d * w1.w + b1.w, 0.f) * w2.w;
                    bias[j][jm] = bacc;
                }
        }

        // ---- mask, softmax per query ----
        float inv[4];
        const float bd2h = bd2[h];
#pragma unroll
        for (int j = 0; j < 4; ++j) {
            float s[4];
#pragma unroll
            for (int jm = 0; jm < 4; ++jm) {
                s[jm] = acc[j][jm] + bias[j][jm] + bd2h;
                if (mk[jm] == 0) s[jm] = -1e30f;
            }
            float mx = fmaxf(fmaxf(s[0], s[1]), fmaxf(s[2], s[3]));
#pragma unroll
            for (int off = 32; off > 0; off >>= 1) mx = fmaxf(mx, __shfl_xor(mx, off, 64));
            float e0 = __expf(s[0] - mx), e1 = __expf(s[1] - mx);
            float e2 = __expf(s[2] - mx), e3 = __expf(s[3] - mx);
            ((float4*)sw[h][j])[lane] = make_float4(e0, e1, e2, e3);
            float sum = e0 + e1 + e2 + e3;
#pragma unroll
            for (int off = 32; off > 0; off >>= 1) sum += __shfl_xor(sum, off, 64);
            inv[j] = 1.0f / sum;
        }
        // sw rows are wave-private (per head): no block sync needed before PV.

        // ---- PV: lane -> (mo, d4); each V load reused for 4 queries ----
        const int mo = lane >> 4, d4 = lane & 15;
        const float* vbase = Yv + (size_t)b * Nc * Dc + h * HDc + d4 * 4;
        f4v o[4];
#pragma unroll
        for (int j = 0; j < 4; ++j) o[j] = (f4v)(0.f);
#pragma unroll 8
        for (int mq = 0; mq < 64; ++mq) {
            const int m = mq * 4 + mo;
            const f4v v = *(const f4v*)&vbase[(size_t)m * Dc];
#pragma unroll
            for (int j = 0; j < 4; ++j) o[j] += sw[h][j][m] * v;
        }
#pragma unroll
        for (int j = 0; j < 4; ++j) {
#pragma unroll
            for (int off = 16; off <= 32; off <<= 1) {
                o[j].x += __shfl_xor(o[j].x, off, 64);
                o[j].y += __shfl_xor(o[j].y, off, 64);
                o[j].z += __shfl_xor(o[j].z, off, 64);
                o[j].w += __shfl_xor(o[j].w, off, 64);
            }
            if (mo == 0) {
                f4v r = o[j] * inv[j];
                *(f4v*)&sO[j][h * HDc + d4 * 4] = r;
            }
        }
        __syncthreads();

        // ---- O-projection: thread owns column jj for all 4 rows ----------
        {
            const int jj = tid;   // 0..511
            float a0 = 0.f, a1 = 0.f, a2 = 0.f, a3 = 0.f;
#pragma unroll 4
            for (int k4 = 0; k4 < 128; ++k4) {
                const float4 q0 = *(const float4*)&sO[0][k4 * 4];
                const float4 q1 = *(const float4*)&sO[1][k4 * 4];
                const float4 q2 = *(const float4*)&sO[2][k4 * 4];
                const float4 q3 = *(const float4*)&sO[3][k4 * 4];
                const float w0 = WoT[(size_t)(k4 * 4 + 0) * Dc + jj];
                const float w1 = WoT[(size_t)(k4 * 4 + 1) * Dc + jj];
                const float w2 = WoT[(size_t)(k4 * 4 + 2) * Dc + jj];
                const float w3 = WoT[(size_t)(k4 * 4 + 3) * Dc + jj];
                a0 += q0.x * w0; a0 += q0.y * w1; a0 += q0.z * w2; a0 += q0.w * w3;
                a1 += q1.x * w0; a1 += q1.y * w1; a1 += q1.z * w2; a1 += q1.w * w3;
                a2 += q2.x * w0; a2 += q2.y * w1; a2 += q2.z * w2; a2 += q2.w * w3;
                a3 += q3.x * w0; a3 += q3.y * w1; a3 += q3.z * w2; a3 += q3.w * w3;
            }
            const float bj = bo[jj];
            sOut[0][jj] = a0 + bj;
            sOut[1][jj] = a1 + bj;
            sOut[2][jj] = a2 + bj;
            sOut[3][jj] = a3 + bj;
        }
        __syncthreads();

        // ---- T-broadcast: fully contiguous nontemporal writes ------------
        {
            const int c0 = tid & 127;       // float4 column
            const int tg = tid >> 7;        // t-quarter 0..3
#pragma unroll
            for (int q = 0; q < 4; ++q) {
                const f4v val = *(const f4v*)&sOut[q][c0 * 4];
                f4v* rb = (f4v*)(out + (((size_t)(b * Nc + n4 + q)) * Tc + tg * 32) * Dc) + c0;
#pragma unroll 8
                for (int tt = 0; tt < 32; ++tt) {
                    __builtin_nontemporal_store(val, rb);
                    rb += Dc / 4;
                }
            }
        }
        asm volatile("" ::: "memory");
        __syncthreads();
    }
}

extern "C" void kernel_launch(void* const* d_in, const int* in_sizes, int n_in,
                              void* d_out, int out_size, void* d_ws, size_t ws_size,
                              hipStream_t stream) {
    const float* x      = (const float*)d_in[0];
    const float* coords = (const float*)d_in[1];
    const int*   smask  = (const int*)d_in[2];
    const float* Wq = (const float*)d_in[3];  const float* bq = (const float*)d_in[4];
    const float* Wk = (const float*)d_in[5];  const float* bk = (const float*)d_in[6];
    const float* Wv = (const float*)d_in[7];  const float* bv = (const float*)d_in[8];
    const float* Wo = (const float*)d_in[9];  const float* bo = (const float*)d_in[10];
    const float* Wd1 = (const float*)d_in[11]; const float* bd1 = (const float*)d_in[12];
    const float* Wd2 = (const float*)d_in[13]; const float* bd2 = (const float*)d_in[14];
    float* out = (float*)d_out;

    float* ws    = (float*)d_ws;
    const size_t BND = (size_t)Bc * Nc * Dc;  // 524288
    float* xr    = ws;
    float* Yq    = xr + BND;
    float* Kt    = Yq + BND;   // transposed K
    float* Yv    = Kt + BND;
    float* WoT   = Yv + BND;   // transposed Wo (512x512)

    mean_kernel<<<Bc * Nc, 256, 0, stream>>>(x, xr, Wo, WoT);
    qkv_kernel<<<dim3(16, 24), 256, 0, stream>>>(xr, Wq, bq, Wk, bk, Wv, bv, Yq, Kt, Yv);
    attn_oproj_kernel<<<Bc * 64, 512, 0, stream>>>(Yq, Kt, Yv, coords, smask,
                                                   Wd1, bd1, Wd2, bd2, WoT, bo, out);
}

// Round 6
// 580.199 us; speedup vs baseline: 1.4740x; 1.4740x over previous
//
#include <hip/hip_runtime.h>
#include <math.h>

#define Bc 4
#define Nc 256
#define Tc 128
#define Dc 512
#define Hc 8
#define HDc 64

typedef float f4v __attribute__((ext_vector_type(4)));

// swizzled float4-unit index for 64x64 float tile stored as 1024 float4s
#define SWZ(row, k4) (((row) << 4) | ((k4) ^ (((row) >> 2) & 15)))

// ---------------- Kernel 1: x_repr = mean over T (+ Wo transpose) --------
__global__ __launch_bounds__(256) void mean_kernel(const float* __restrict__ x,
                                                   float* __restrict__ xr,
                                                   const float* __restrict__ Wo,
                                                   float* __restrict__ WoT) {
    __shared__ f4v red[256];
    const int bn = blockIdx.x;
    const int col = threadIdx.x & 127;
    const int half = threadIdx.x >> 7;
    const f4v* xp = (const f4v*)x + (size_t)bn * (Tc * Dc / 4)
                    + (size_t)(half * 64) * (Dc / 4) + col;
    f4v a[8];
#pragma unroll
    for (int u = 0; u < 8; ++u) a[u] = (f4v)(0.f);
    for (int t = 0; t < 64; t += 8) {
#pragma unroll
        for (int u = 0; u < 8; ++u)
            a[u] += __builtin_nontemporal_load(xp + (size_t)(t + u) * (Dc / 4));
    }
    f4v s = ((a[0] + a[1]) + (a[2] + a[3])) + ((a[4] + a[5]) + (a[6] + a[7]));
    red[threadIdx.x] = s;
    __syncthreads();
    if (threadIdx.x < 128) {
        f4v r = (red[threadIdx.x] + red[threadIdx.x + 128]) * (1.0f / Tc);
        ((f4v*)xr)[(size_t)bn * (Dc / 4) + threadIdx.x] = r;
    }
    if (bn < 16) {  // Wo transpose: rows bn*32..+31 -> WoT[k][j]
        const int r0 = bn * 32;
#pragma unroll 4
        for (int u = 0; u < 16; ++u) {
            const int job = u * 256 + threadIdx.x;
            const int r = job >> 7;        // 0..31
            const int k4 = job & 127;      // 0..127
            const float4 v = *(const float4*)&Wo[(size_t)(r0 + r) * Dc + k4 * 4];
            WoT[(size_t)(k4 * 4 + 0) * Dc + r0 + r] = v.x;
            WoT[(size_t)(k4 * 4 + 1) * Dc + r0 + r] = v.y;
            WoT[(size_t)(k4 * 4 + 2) * Dc + r0 + r] = v.z;
            WoT[(size_t)(k4 * 4 + 3) * Dc + r0 + r] = v.w;
        }
    }
}

// ---------------- GEMM core with register-prefetch pipeline --------------
__device__ __forceinline__ void gemm_core(const float* __restrict__ A,
                                          const float* __restrict__ W,
                                          int i0, int j0, float acc[4][4]) {
    __shared__ float4 As4[1024];
    __shared__ float4 Ws4[1024];
    const int tid = threadIdx.x;
    const int ty = tid >> 4, tx = tid & 15;
    float4 pa[4], pw[4];
#pragma unroll
    for (int p = 0; p < 4; ++p) {
        pa[p] = *(const float4*)&A[(size_t)(i0 + p * 16 + ty) * Dc + tx * 4];
        pw[p] = *(const float4*)&W[(size_t)(j0 + p * 16 + ty) * Dc + tx * 4];
    }
    for (int kb = 0; kb < 8; ++kb) {
#pragma unroll
        for (int p = 0; p < 4; ++p) {
            As4[SWZ(p * 16 + ty, tx)] = pa[p];
            Ws4[SWZ(p * 16 + ty, tx)] = pw[p];
        }
        __syncthreads();
        if (kb < 7) {
            const int k0 = (kb + 1) * 64;
#pragma unroll
            for (int p = 0; p < 4; ++p) {
                pa[p] = *(const float4*)&A[(size_t)(i0 + p * 16 + ty) * Dc + k0 + tx * 4];
                pw[p] = *(const float4*)&W[(size_t)(j0 + p * 16 + ty) * Dc + k0 + tx * 4];
            }
        }
#pragma unroll
        for (int kk4 = 0; kk4 < 16; ++kk4) {
            float4 a[4], w[4];
#pragma unroll
            for (int q = 0; q < 4; ++q) a[q] = As4[SWZ(ty * 4 + q, kk4)];
#pragma unroll
            for (int c = 0; c < 4; ++c) w[c] = Ws4[SWZ(tx * 4 + c, kk4)];
#pragma unroll
            for (int q = 0; q < 4; ++q)
#pragma unroll
                for (int c = 0; c < 4; ++c) {
                    acc[q][c] += a[q].x * w[c].x;
                    acc[q][c] += a[q].y * w[c].y;
                    acc[q][c] += a[q].z * w[c].z;
                    acc[q][c] += a[q].w * w[c].w;
                }
        }
        __syncthreads();
    }
}

// Fused QKV: grid (16, 24). K stored TRANSPOSED: Kt[((b*8+h)*64+hd)*256+n]
__global__ __launch_bounds__(256) void qkv_kernel(
    const float* __restrict__ xr, const float* __restrict__ Wq, const float* __restrict__ bq,
    const float* __restrict__ Wk, const float* __restrict__ bk,
    const float* __restrict__ Wv, const float* __restrict__ bv,
    float* __restrict__ Yq, float* __restrict__ Kt, float* __restrict__ Yv) {
    const int it = blockIdx.x;
    const int mat = blockIdx.y >> 3;
    const int jt = blockIdx.y & 7;
    const float* W = (mat == 0) ? Wq : (mat == 1) ? Wk : Wv;
    const float* bias = (mat == 0) ? bq : (mat == 1) ? bk : bv;
    const int i0 = it * 64, j0 = jt * 64;
    float acc[4][4] = {{0.f}};
    gemm_core(xr, W, i0, j0, acc);
    const int ty = threadIdx.x >> 4, tx = threadIdx.x & 15;
    if (mat == 1) {
        const int b = i0 >> 8;
        const int n0 = (i0 & 255) + ty * 4;
#pragma unroll
        for (int c = 0; c < 4; ++c) {
            const int j = j0 + tx * 4 + c;
            const float bj = bias[j];
            float4 v = make_float4(acc[0][c] + bj, acc[1][c] + bj,
                                   acc[2][c] + bj, acc[3][c] + bj);
            *(float4*)&Kt[(((size_t)b * Hc + jt) * HDc + (tx * 4 + c)) * Nc + n0] = v;
        }
    } else {
        float* Y = (mat == 0) ? Yq : Yv;
#pragma unroll
        for (int r = 0; r < 4; ++r) {
            const int i = i0 + ty * 4 + r;
            const int j = j0 + tx * 4;
            float4 o = make_float4(acc[r][0] + bias[j + 0], acc[r][1] + bias[j + 1],
                                   acc[r][2] + bias[j + 2], acc[r][3] + bias[j + 3]);
            *(float4*)&Y[(size_t)i * Dc + j] = o;
        }
    }
}

// ---------------- Kernel 3: attention + O-proj + T-broadcast -------------
// 512 blocks = (b, 2-query group) -> 2 blocks/CU so one block's write
// burst overlaps the co-resident block's compute phase. 512 threads =
// 8 waves, wave w = head w. All per-(row,pair) FP chains identical to
// the round-4 kernel (bit-identical output).
__global__ __launch_bounds__(512) void attn_oproj_kernel(
    const float* __restrict__ Yq, const float* __restrict__ Kt,
    const float* __restrict__ Yv, const float* __restrict__ coords,
    const int* __restrict__ mask, const float* __restrict__ Wd1,
    const float* __restrict__ bd1, const float* __restrict__ Wd2,
    const float* __restrict__ bd2, const float* __restrict__ WoT,
    const float* __restrict__ bo, float* __restrict__ out) {
    const int b = blockIdx.x >> 7;
    const int n2 = (blockIdx.x & 127) * 2;   // 2 query rows per block
    const int tid = threadIdx.x;
    const int wid = tid >> 6, lane = tid & 63;
    const int h = wid;                       // wave = head

    __shared__ __align__(16) float sqf[2][512];     // q rows (all heads), scaled
    __shared__ __align__(16) float sw[8][2][256];   // softmax numerators
    __shared__ __align__(16) float sO[2][512];      // attention-out rows
    __shared__ __align__(16) float sOut[2][512];    // final out rows
    __shared__ float slat[256], slon[256], scl[256];
    __shared__ __align__(16) float swd1[64];
    __shared__ __align__(16) float sbd1[64];
    __shared__ __align__(16) float swd2[512];       // all 8 heads
    __shared__ int smk[256];

    {
        const float DEG = 0.017453292519943295f;
        if (tid < 256) {
            float la = coords[((size_t)b * Nc + tid) * 2 + 0] * DEG;
            float lo = coords[((size_t)b * Nc + tid) * 2 + 1] * DEG;
            slat[tid] = la; slon[tid] = lo; scl[tid] = __cosf(la);
            smk[tid] = mask[(size_t)b * Nc + tid];
            const int row = tid >> 7, c4 = tid & 127;
            const float4 qv = *(const float4*)&Yq[((size_t)(b * Nc + n2 + row)) * Dc + c4 * 4];
            sqf[row][c4 * 4 + 0] = qv.x * 0.125f;
            sqf[row][c4 * 4 + 1] = qv.y * 0.125f;
            sqf[row][c4 * 4 + 2] = qv.z * 0.125f;
            sqf[row][c4 * 4 + 3] = qv.w * 0.125f;
        }
        if (tid < 64) {
            swd1[tid] = Wd1[tid];
            sbd1[tid] = bd1[tid];
        }
        swd2[tid] = Wd2[tid];
    }
    __syncthreads();

    // ---- scores: lane owns m-strip lane*4..+3 for 2 queries (head h) ----
    const float4* ktp = (const float4*)(Kt + ((size_t)(b * Hc + h)) * HDc * Nc);
    f4v acc[2];
#pragma unroll
    for (int j = 0; j < 2; ++j) acc[j] = (f4v)(0.f);
#pragma unroll 8
    for (int k = 0; k < 64; ++k) {
        const float4 kv = ktp[k * 64 + lane];
        const f4v kvv = {kv.x, kv.y, kv.z, kv.w};
#pragma unroll
        for (int j = 0; j < 2; ++j) acc[j] += sqf[j][h * HDc + k] * kvv;
    }

    // ---- haversine distances for all 8 (j, jm) pairs ----
    const int mbase = lane * 4;
    float mlat[4], mlon[4], mcl[4];
    int mk[4];
#pragma unroll
    for (int jm = 0; jm < 4; ++jm) {
        mlat[jm] = slat[mbase + jm]; mlon[jm] = slon[mbase + jm];
        mcl[jm] = scl[mbase + jm];   mk[jm] = smk[mbase + jm];
    }
    float dist[2][4];
#pragma unroll
    for (int j = 0; j < 2; ++j) {
        const int n = n2 + j;
        const float lat1 = slat[n], lon1 = slon[n], cl1 = scl[n];
#pragma unroll
        for (int jm = 0; jm < 4; ++jm) {
            float sdlat = __sinf((mlat[jm] - lat1) * 0.5f);
            float sdlon = __sinf((mlon[jm] - lon1) * 0.5f);
            float a = sdlat * sdlat + cl1 * mcl[jm] * sdlon * sdlon;
            a = fminf(fmaxf(a, 0.f), 1.f);
            dist[j][jm] = 12742.0f * atan2f(sqrtf(a), sqrtf(1.0f - a));
        }
    }

    // ---- MLP bias: k4-outer, pairs-inner (strict k-ascending adds) ----
    float bias[2][4];
#pragma unroll
    for (int j = 0; j < 2; ++j)
#pragma unroll
        for (int jm = 0; jm < 4; ++jm) bias[j][jm] = 0.f;
#pragma unroll 4
    for (int k4 = 0; k4 < 16; ++k4) {
        const float4 w1 = *(const float4*)&swd1[k4 * 4];
        const float4 b1 = *(const float4*)&sbd1[k4 * 4];
        const float4 w2 = *(const float4*)&swd2[h * HDc + k4 * 4];
#pragma unroll
        for (int j = 0; j < 2; ++j)
#pragma unroll
            for (int jm = 0; jm < 4; ++jm) {
                const float d = dist[j][jm];
                float bacc = bias[j][jm];
                bacc += fmaxf(d * w1.x + b1.x, 0.f) * w2.x;
                bacc += fmaxf(d * w1.y + b1.y, 0.f) * w2.y;
                bacc += fmaxf(d * w1.z + b1.z, 0.f) * w2.z;
                bacc += fmaxf(d * w1.w + b1.w, 0.f) * w2.w;
                bias[j][jm] = bacc;
            }
    }

    // ---- mask, softmax per query ----
    float inv[2];
    const float bd2h = bd2[h];
#pragma unroll
    for (int j = 0; j < 2; ++j) {
        float s[4];
#pragma unroll
        for (int jm = 0; jm < 4; ++jm) {
            s[jm] = acc[j][jm] + bias[j][jm] + bd2h;
            if (mk[jm] == 0) s[jm] = -1e30f;
        }
        float mx = fmaxf(fmaxf(s[0], s[1]), fmaxf(s[2], s[3]));
#pragma unroll
        for (int off = 32; off > 0; off >>= 1) mx = fmaxf(mx, __shfl_xor(mx, off, 64));
        float e0 = __expf(s[0] - mx), e1 = __expf(s[1] - mx);
        float e2 = __expf(s[2] - mx), e3 = __expf(s[3] - mx);
        ((float4*)sw[h][j])[lane] = make_float4(e0, e1, e2, e3);
        float sum = e0 + e1 + e2 + e3;
#pragma unroll
        for (int off = 32; off > 0; off >>= 1) sum += __shfl_xor(sum, off, 64);
        inv[j] = 1.0f / sum;
    }
    // sw rows are wave-private (per head): no block sync needed before PV.

    // ---- PV: lane -> (mo, d4); each V load reused for 2 queries ----
    const int mo = lane >> 4, d4 = lane & 15;
    const float* vbase = Yv + (size_t)b * Nc * Dc + h * HDc + d4 * 4;
    f4v o[2];
#pragma unroll
    for (int j = 0; j < 2; ++j) o[j] = (f4v)(0.f);
#pragma unroll 8
    for (int mq = 0; mq < 64; ++mq) {
        const int m = mq * 4 + mo;
        const f4v v = *(const f4v*)&vbase[(size_t)m * Dc];
#pragma unroll
        for (int j = 0; j < 2; ++j) o[j] += sw[h][j][m] * v;
    }
#pragma unroll
    for (int j = 0; j < 2; ++j) {
#pragma unroll
        for (int off = 16; off <= 32; off <<= 1) {
            o[j].x += __shfl_xor(o[j].x, off, 64);
            o[j].y += __shfl_xor(o[j].y, off, 64);
            o[j].z += __shfl_xor(o[j].z, off, 64);
            o[j].w += __shfl_xor(o[j].w, off, 64);
        }
        if (mo == 0) {
            f4v r = o[j] * inv[j];
            *(f4v*)&sO[j][h * HDc + d4 * 4] = r;
        }
    }
    __syncthreads();

    // ---- O-projection: thread owns column jj for both rows -----------
    // k ascending scalar chain == gemm_core's kb->kk4->xyzw order.
    {
        const int jj = tid;   // 0..511
        float a0 = 0.f, a1 = 0.f;
#pragma unroll 4
        for (int k4 = 0; k4 < 128; ++k4) {
            const float4 q0 = *(const float4*)&sO[0][k4 * 4];
            const float4 q1 = *(const float4*)&sO[1][k4 * 4];
            const float w0 = WoT[(size_t)(k4 * 4 + 0) * Dc + jj];
            const float w1 = WoT[(size_t)(k4 * 4 + 1) * Dc + jj];
            const float w2 = WoT[(size_t)(k4 * 4 + 2) * Dc + jj];
            const float w3 = WoT[(size_t)(k4 * 4 + 3) * Dc + jj];
            a0 += q0.x * w0; a0 += q0.y * w1; a0 += q0.z * w2; a0 += q0.w * w3;
            a1 += q1.x * w0; a1 += q1.y * w1; a1 += q1.z * w2; a1 += q1.w * w3;
        }
        const float bj = bo[jj];
        sOut[0][jj] = a0 + bj;
        sOut[1][jj] = a1 + bj;
    }
    __syncthreads();

    // ---- T-broadcast: fully contiguous nontemporal writes ------------
    {
        const int c0 = tid & 127;       // float4 column
        const int tg = tid >> 7;        // t-quarter 0..3
#pragma unroll
        for (int q = 0; q < 2; ++q) {
            const f4v val = *(const f4v*)&sOut[q][c0 * 4];
            f4v* rb = (f4v*)(out + (((size_t)(b * Nc + n2 + q)) * Tc + tg * 32) * Dc) + c0;
#pragma unroll 8
            for (int tt = 0; tt < 32; ++tt) {
                __builtin_nontemporal_store(val, rb);
                rb += Dc / 4;
            }
        }
    }
}

extern "C" void kernel_launch(void* const* d_in, const int* in_sizes, int n_in,
                              void* d_out, int out_size, void* d_ws, size_t ws_size,
                              hipStream_t stream) {
    const float* x      = (const float*)d_in[0];
    const float* coords = (const float*)d_in[1];
    const int*   smask  = (const int*)d_in[2];
    const float* Wq = (const float*)d_in[3];  const float* bq = (const float*)d_in[4];
    const float* Wk = (const float*)d_in[5];  const float* bk = (const float*)d_in[6];
    const float* Wv = (const float*)d_in[7];  const float* bv = (const float*)d_in[8];
    const float* Wo = (const float*)d_in[9];  const float* bo = (const float*)d_in[10];
    const float* Wd1 = (const float*)d_in[11]; const float* bd1 = (const float*)d_in[12];
    const float* Wd2 = (const float*)d_in[13]; const float* bd2 = (const float*)d_in[14];
    float* out = (float*)d_out;

    float* ws    = (float*)d_ws;
    const size_t BND = (size_t)Bc * Nc * Dc;  // 524288
    float* xr    = ws;
    float* Yq    = xr + BND;
    float* Kt    = Yq + BND;   // transposed K
    float* Yv    = Kt + BND;
    float* WoT   = Yv + BND;   // transposed Wo (512x512)

    mean_kernel<<<Bc * Nc, 256, 0, stream>>>(x, xr, Wo, WoT);
    qkv_kernel<<<dim3(16, 24), 256, 0, stream>>>(xr, Wq, bq, Wk, bk, Wv, bv, Yq, Kt, Yv);
    attn_oproj_kernel<<<Bc * 128, 512, 0, stream>>>(Yq, Kt, Yv, coords, smask,
                                                    Wd1, bd1, Wd2, bd2, WoT, bo, out);
}